// Round 4
// baseline (729.093 us; speedup 1.0000x reference)
//
#include <hip/hip_runtime.h>
#include <hip/hip_bf16.h>
#include <hip/hip_cooperative_groups.h>
#include <math.h>

namespace cg = cooperative_groups;

// Problem constants
#define NB 32768   // batch
#define NH 256     // hidden = nsync
#define NI 128     // input
// out layout (f32): h[8388608] | alpha[8388608] | beta[8388608] | last[1]

typedef __attribute__((ext_vector_type(8))) short short8;  // 8 x bf16 mfma frag
typedef __attribute__((ext_vector_type(4))) float f32x4;   // mfma accum

__device__ __forceinline__ float b2f(unsigned int u) {
    union { float f; unsigned int i; } v; v.i = (u & 0xffffu) << 16; return v.f;
}
__device__ __forceinline__ unsigned short f2b(float f) {
    union { float f; unsigned int i; } v; v.f = f;
    unsigned int x = v.i;
    return (unsigned short)((x + 0x7fffu + ((x >> 16) & 1u)) >> 16);
}
__device__ __forceinline__ void unpack8(uint4 v, float* o) {
    o[0]=b2f(v.x); o[1]=b2f(v.x>>16);
    o[2]=b2f(v.y); o[3]=b2f(v.y>>16);
    o[4]=b2f(v.z); o[5]=b2f(v.z>>16);
    o[6]=b2f(v.w); o[7]=b2f(v.w>>16);
}
__device__ __forceinline__ uint4 pack8(const float* f) {
    uint4 r;
    r.x = (unsigned)f2b(f[0]) | ((unsigned)f2b(f[1])<<16);
    r.y = (unsigned)f2b(f[2]) | ((unsigned)f2b(f[3])<<16);
    r.z = (unsigned)f2b(f[4]) | ((unsigned)f2b(f[5])<<16);
    r.w = (unsigned)f2b(f[6]) | ((unsigned)f2b(f[7])<<16);
    return r;
}

// ===========================================================================
// PRIMARY: persistent cooperative kernel. 512 blocks x 256 threads, 2/CU.
// Block owns rows [bid*64, bid*64+64). h in LDS (bf16 swizzled); alpha f32 +
// beta0 bf16 in regs; basex fragments in global ws (coalesced uint4).
// W read directly from global (L2-resident) as MFMA B-fragments.
// ===========================================================================
__global__ __launch_bounds__(256, 2) void k_persist(
        const float* __restrict__ x, const float* __restrict__ h0,
        const float* __restrict__ alpha0, const float* __restrict__ beta0,
        const float* __restrict__ Wf, const float* __restrict__ bfv,
        const float* __restrict__ tau, const float* __restrict__ rparam,
        const float* __restrict__ Aparam, const float* __restrict__ Wm,
        const int* __restrict__ idxl, const int* __restrict__ idxr,
        unsigned short* __restrict__ wsW, float* __restrict__ norms,
        uint4* __restrict__ bxg, float* __restrict__ out) {
    __shared__ unsigned short sH[64 * 256];   // 32KB h state (swizzled)
    __shared__ unsigned short sS[64 * 256];   // 32KB x-stage / sync / hu
    __shared__ int   pIdx[256];               // idxl | idxr<<16
    __shared__ float rsL[256];                // sigmoid(r_param)
    __shared__ float red[8];

    const int tid = threadIdx.x, bid = blockIdx.x;
    const int r0 = bid * 64;
    const int gt = bid * 256 + tid;

    // ---- per-block param LDS
    rsL[tid]  = 1.0f / (1.0f + __expf(-rparam[tid]));
    pIdx[tid] = (idxl[tid] & 0xffff) | (idxr[tid] << 16);

    // ---- global W build (bf16 slices, K-chunks of 32): [Wfx|Wfh|Wm]
    if (gt < 20480) {
        int s = gt >> 10, rem = gt & 1023;
        int n = rem >> 2, q = rem & 3;
        float vals[8];
        #pragma unroll
        for (int j = 0; j < 8; ++j) {
            int kg = s * 32 + q * 8 + j;
            vals[j] = (kg < 384) ? Wf[n * 384 + kg] : Wm[n * 256 + (kg - 384)];
        }
        *(uint4*)(wsW + s * 8192 + (n * 4 + q) * 8) = pack8(vals);
    }
    if (gt >= 20480 && gt < 20488) norms[gt - 20480] = 0.0f;

    // ---- persistent per-thread state (phase-B mapping: row=tid>>2, 64 cols)
    const int prow = tid >> 2;
    const int pc0  = (tid & 3) * 64;
    const unsigned pswz = (unsigned)((prow & 7) << 4);

    float    al[64];     // alpha, f32
    unsigned b0p[32];    // beta0, packed bf16 pairs

    // h0 -> sH (bf16, swizzled)
    #pragma unroll
    for (int q = 0; q < 8; ++q) {
        int c = pc0 + q * 8;
        float4 v0 = *(const float4*)(h0 + (r0 + prow) * 256 + c);
        float4 v1 = *(const float4*)(h0 + (r0 + prow) * 256 + c + 4);
        float vf[8] = {v0.x, v0.y, v0.z, v0.w, v1.x, v1.y, v1.z, v1.w};
        *(uint4*)((char*)sH + (((unsigned)(prow * 512 + c * 2)) ^ pswz)) = pack8(vf);
    }
    // alpha0 -> regs (f32)
    #pragma unroll
    for (int q = 0; q < 16; ++q) {
        float4 v = *(const float4*)(alpha0 + (r0 + prow) * 256 + pc0 + q * 4);
        al[q*4+0] = v.x; al[q*4+1] = v.y; al[q*4+2] = v.z; al[q*4+3] = v.w;
    }
    // beta0 -> bf16 packed regs
    #pragma unroll
    for (int q = 0; q < 8; ++q) {
        float4 v0 = *(const float4*)(beta0 + (r0 + prow) * 256 + pc0 + q * 8);
        float4 v1 = *(const float4*)(beta0 + (r0 + prow) * 256 + pc0 + q * 8 + 4);
        b0p[q*4+0] = (unsigned)f2b(v0.x) | ((unsigned)f2b(v0.y) << 16);
        b0p[q*4+1] = (unsigned)f2b(v0.z) | ((unsigned)f2b(v0.w) << 16);
        b0p[q*4+2] = (unsigned)f2b(v1.x) | ((unsigned)f2b(v1.y) << 16);
        b0p[q*4+3] = (unsigned)f2b(v1.z) | ((unsigned)f2b(v1.w) << 16);
    }
    // x tile -> sS (bf16, 64x128, swizzled; row stride 256B)
    #pragma unroll
    for (int q = 0; q < 4; ++q) {
        int c = (tid & 3) * 32 + q * 8;
        float4 v0 = *(const float4*)(x + (r0 + prow) * 128 + c);
        float4 v1 = *(const float4*)(x + (r0 + prow) * 128 + c + 4);
        float vf[8] = {v0.x, v0.y, v0.z, v0.w, v1.x, v1.y, v1.z, v1.w};
        *(uint4*)((char*)sS + (((unsigned)(prow * 256 + c * 2)) ^ pswz)) = pack8(vf);
    }
    __syncthreads();

    cg::grid_group grid = cg::this_grid();
    grid.sync();   // W complete + norms zeroed, device-wide

    // ---- MFMA geometry
    const int wave = tid >> 6, lane = tid & 63, lrow = lane & 15, lq = lane >> 4;
    const unsigned aswz = (unsigned)((lrow & 7) << 4);
    const unsigned short* wbase = wsW + (size_t)(((wave * 64 + lrow) * 4 + lq) * 8);

    // ---- basex GEMM: x(64x128) @ Wfx^T + bf -> global bxg (coalesced uint4)
    {
        f32x4 acc[4][4];
        #pragma unroll
        for (int m = 0; m < 4; ++m)
            #pragma unroll
            for (int n = 0; n < 4; ++n) { f32x4 z = {0.f,0.f,0.f,0.f}; acc[m][n] = z; }
        #pragma unroll 1
        for (int kk = 0; kk < 4; ++kk) {
            short8 bfr[4];
            #pragma unroll
            for (int n = 0; n < 4; ++n)
                bfr[n] = *(const short8*)(wbase + kk * 8192 + n * 512);
            short8 a[4];
            int k = kk * 32 + lq * 8;
            #pragma unroll
            for (int m = 0; m < 4; ++m) {
                unsigned byte = ((unsigned)((m * 16 + lrow) * 256 + k * 2)) ^ aswz;
                a[m] = *(const short8*)((const char*)sS + byte);
            }
            #pragma unroll
            for (int m = 0; m < 4; ++m)
                #pragma unroll
                for (int n = 0; n < 4; ++n)
                    acc[m][n] = __builtin_amdgcn_mfma_f32_16x16x32_bf16(a[m], bfr[n], acc[m][n], 0, 0, 0);
        }
        unsigned u[32];
        #pragma unroll
        for (int m = 0; m < 4; ++m)
            #pragma unroll
            for (int n = 0; n < 4; ++n) {
                float bias = bfv[wave * 64 + n * 16 + lrow];
                int f = m * 4 + n;
                u[2*f]   = (unsigned)f2b(acc[m][n][0] + bias) | ((unsigned)f2b(acc[m][n][1] + bias) << 16);
                u[2*f+1] = (unsigned)f2b(acc[m][n][2] + bias) | ((unsigned)f2b(acc[m][n][3] + bias) << 16);
            }
        #pragma unroll
        for (int q = 0; q < 8; ++q)
            bxg[q * 131072 + gt] = make_uint4(u[4*q], u[4*q+1], u[4*q+2], u[4*q+3]);
    }
    float Areg[4];
    #pragma unroll
    for (int n = 0; n < 4; ++n) Areg[n] = Aparam[wave * 64 + n * 16 + lrow];
    const float inv_tau = 1.0f / log1pf(expf(tau[0]));
    __syncthreads();   // sS (x tile) consumed

    // ---- 6 recurrent steps
    bool done = false;
    int lasts = 0;
    const unsigned short* wstep = wsW + 4 * 8192;   // slices 4..19

    for (int t = 0; t < 6; ++t) {
        if (!done) {
            lasts = t;
            // phase B: alpha/beta/sync -> sS (bf16 swizzled)
            #pragma unroll
            for (int q = 0; q < 8; ++q) {
                float sy[8];
                #pragma unroll
                for (int jj = 0; jj < 8; ++jj) {
                    int j = q * 8 + jj;
                    int c = pc0 + j;
                    int pr = pIdx[c];
                    float hl = b2f(*(const unsigned short*)((const char*)sH +
                               (((unsigned)(prow * 512 + (pr & 0xffff) * 2)) ^ pswz)));
                    float hr = b2f(*(const unsigned short*)((const char*)sH +
                               (((unsigned)(prow * 512 + (pr >> 16) * 2)) ^ pswz)));
                    float rr = rsL[c];
                    float av = rr * al[j] + hl * hr;
                    al[j] = av;
                    float p = 1.0f, ssum = 0.0f;
                    for (int u = 0; u <= t; ++u) { ssum += p; p *= rr; }
                    float b0v = b2f(b0p[j >> 1] >> ((j & 1) * 16));
                    float bt = p * b0v + ssum;
                    sy[jj] = av / (sqrtf(bt) + 1e-6f);
                }
                *(uint4*)((char*)sS + (((unsigned)(prow * 512 + (pc0 + q * 8) * 2)) ^ pswz)) = pack8(sy);
            }
            __syncthreads();

            // GEMM: [h | sync] (64x512) @ [Wfh|Wm]^T
            f32x4 acc[4][4];
            #pragma unroll
            for (int m = 0; m < 4; ++m)
                #pragma unroll
                for (int n = 0; n < 4; ++n) { f32x4 z = {0.f,0.f,0.f,0.f}; acc[m][n] = z; }
            #pragma unroll 1
            for (int kk = 0; kk < 16; ++kk) {
                short8 bfr[4];
                #pragma unroll
                for (int n = 0; n < 4; ++n)
                    bfr[n] = *(const short8*)(wstep + kk * 8192 + (wbase - wsW) + n * 512);
                short8 a[4];
                if (kk < 8) {
                    int k = kk * 32 + lq * 8;
                    #pragma unroll
                    for (int m = 0; m < 4; ++m) {
                        unsigned byte = ((unsigned)((m * 16 + lrow) * 512 + k * 2)) ^ aswz;
                        a[m] = *(const short8*)((const char*)sH + byte);
                    }
                } else {
                    int k = (kk - 8) * 32 + lq * 8;
                    #pragma unroll
                    for (int m = 0; m < 4; ++m) {
                        unsigned byte = ((unsigned)((m * 16 + lrow) * 512 + k * 2)) ^ aswz;
                        a[m] = *(const short8*)((const char*)sS + byte);
                    }
                }
                #pragma unroll
                for (int m = 0; m < 4; ++m)
                    #pragma unroll
                    for (int n = 0; n < 4; ++n)
                        acc[m][n] = __builtin_amdgcn_mfma_f32_16x16x32_bf16(a[m], bfr[n], acc[m][n], 0, 0, 0);
            }
            __syncthreads();   // sS (sync) consumed; reuse for hu

            // epilogue: hu -> sS (C-layout scattered), norm partial
            uint4 bxl[8];
            #pragma unroll
            for (int q = 0; q < 8; ++q) bxl[q] = bxg[q * 131072 + gt];
            float tsum = 0.0f;
            #pragma unroll
            for (int m = 0; m < 4; ++m)
                #pragma unroll
                for (int n = 0; n < 4; ++n) {
                    int f = m * 4 + n;
                    unsigned lo = (f & 1) ? bxl[f >> 1].z : bxl[f >> 1].x;
                    unsigned hi = (f & 1) ? bxl[f >> 1].w : bxl[f >> 1].y;
                    float bxf[4] = {b2f(lo), b2f(lo >> 16), b2f(hi), b2f(hi >> 16)};
                    #pragma unroll
                    for (int r = 0; r < 4; ++r) {
                        int row = m * 16 + lq * 4 + r;
                        int col = wave * 64 + n * 16 + lrow;
                        unsigned byte = ((unsigned)(row * 512 + col * 2)) ^ ((unsigned)((row & 7) << 4));
                        float arg = acc[m][n][r] + bxf[r];
                        float s = __sinf(arg);
                        float fv = s * s;
                        float hv = b2f(*(const unsigned short*)((const char*)sH + byte));
                        float dh = -hv * (inv_tau + fv) + Areg[n] * fv;
                        float huv = 0.1f * dh;
                        *(unsigned short*)((char*)sS + byte) = f2b(huv);
                        tsum += fabsf(huv);
                    }
                }
            #pragma unroll
            for (int d = 32; d >= 1; d >>= 1) tsum += __shfl_down(tsum, d);
            if (lane == 0) red[wave] = tsum;
            __syncthreads();
            if (tid == 0) atomicAdd(&norms[t], red[0] + red[1] + red[2] + red[3]);
        }
        grid.sync();
        if (!done) {
            float nm = __hip_atomic_load(&norms[t], __ATOMIC_RELAXED, __HIP_MEMORY_SCOPE_AGENT)
                       * (1.0f / 8388608.0f);
            bool brk = (t >= 3) && (nm < 0.01f);
            float factor = brk ? 1.0f : 2.0f;
            // h update (vectorized, phase-B mapping)
            #pragma unroll
            for (int q = 0; q < 8; ++q) {
                unsigned byte = ((unsigned)(prow * 512 + (pc0 + q * 8) * 2)) ^ pswz;
                uint4 hv = *(const uint4*)((const char*)sH + byte);
                uint4 uv = *(const uint4*)((const char*)sS + byte);
                float hf[8], uf[8], nf[8];
                unpack8(hv, hf); unpack8(uv, uf);
                #pragma unroll
                for (int j = 0; j < 8; ++j) nf[j] = hf[j] + factor * uf[j];
                *(uint4*)((char*)sH + byte) = pack8(nf);
            }
            done = brk;
            __syncthreads();
        }
    }

    // ---- outputs (f32)
    #pragma unroll
    for (int q = 0; q < 8; ++q) {
        int c = pc0 + q * 8;
        uint4 hv = *(const uint4*)((const char*)sH + (((unsigned)(prow * 512 + c * 2)) ^ pswz));
        float hf[8];
        unpack8(hv, hf);
        *(float4*)(out + (r0 + prow) * 256 + c)     = make_float4(hf[0], hf[1], hf[2], hf[3]);
        *(float4*)(out + (r0 + prow) * 256 + c + 4) = make_float4(hf[4], hf[5], hf[6], hf[7]);
    }
    #pragma unroll
    for (int q = 0; q < 16; ++q)
        *(float4*)(out + 8388608 + (r0 + prow) * 256 + pc0 + q * 4) =
            make_float4(al[q*4+0], al[q*4+1], al[q*4+2], al[q*4+3]);
    int n_exec = lasts + 1;
    #pragma unroll
    for (int q = 0; q < 16; ++q) {
        float bo[4];
        #pragma unroll
        for (int i = 0; i < 4; ++i) {
            int j = q * 4 + i;
            float rr = rsL[pc0 + j];
            float p = 1.0f, ssum = 0.0f;
            for (int u = 0; u < n_exec; ++u) { ssum += p; p *= rr; }
            float b0v = b2f(b0p[j >> 1] >> ((j & 1) * 16));
            bo[i] = p * b0v + ssum;
        }
        *(float4*)(out + 16777216 + (r0 + prow) * 256 + pc0 + q * 4) =
            make_float4(bo[0], bo[1], bo[2], bo[3]);
    }
    if (bid == 0 && tid == 0) out[25165824] = (float)lasts;
}

// ===========================================================================
// FALLBACK: round-2 proven kernel set (verbatim), used if coop launch fails.
// ===========================================================================
struct StepCtl { bool run; bool upd; float factor; };
__device__ __forceinline__ StepCtl step_ctl(const float* norms, int t) {
    bool done = false, done_prev = false, brk_prev = false;
    for (int s = 0; s < t; ++s) {
        bool brk = false;
        if (!done) {
            float nm = norms[s] * (1.0f / 8388608.0f);
            brk = (s >= 3) && (nm < 0.01f);
        }
        if (s == t - 1) { done_prev = done; brk_prev = brk; }
        done = done || brk;
    }
    StepCtl c;
    c.upd = (t > 0) && !done_prev;
    c.factor = brk_prev ? 1.0f : 2.0f;
    c.run = !done;
    return c;
}

__global__ __launch_bounds__(256) void k_init(const float* __restrict__ h0,
                                              const float* __restrict__ Wf,
                                              const float* __restrict__ Wm,
                                              const float* __restrict__ r_param,
                                              unsigned short* __restrict__ h_ws,
                                              unsigned short* __restrict__ wsW,
                                              float* __restrict__ rs,
                                              float* __restrict__ norms) {
    int b = blockIdx.x, tid = threadIdx.x;
    if (b < 8192) {
        int idx4 = (b * 256 + tid) * 4;
        float4 hv = *(const float4*)(h0 + idx4);
        uint2 pk;
        pk.x = (unsigned)f2b(hv.x) | ((unsigned)f2b(hv.y) << 16);
        pk.y = (unsigned)f2b(hv.z) | ((unsigned)f2b(hv.w) << 16);
        *(uint2*)(h_ws + idx4) = pk;
    } else if (b < 8272) {
        int gt = (b - 8192) * 256 + tid;
        int s = gt >> 10;
        int rem = gt & 1023;
        int n = rem >> 2, q = rem & 3;
        float vals[8];
        #pragma unroll
        for (int j = 0; j < 8; ++j) {
            int kg = s * 32 + q * 8 + j;
            vals[j] = (kg < 384) ? Wf[n * 384 + kg] : Wm[n * 256 + (kg - 384)];
        }
        *(uint4*)(wsW + (size_t)s * 8192 + (n * 4 + q) * 8) = pack8(vals);
    } else {
        if (tid < 256) rs[tid] = 1.0f / (1.0f + expf(-r_param[tid]));
        if (tid < 8)   norms[tid] = 0.0f;
    }
}

__global__ __launch_bounds__(256, 2) void k_basex(const float* __restrict__ x,
                                                  const float* __restrict__ bfv,
                                                  const unsigned short* __restrict__ wsW,
                                                  unsigned short* __restrict__ basex) {
    __shared__ unsigned short xA[64 * 128];
    __shared__ unsigned short sW[2 * 8192];
    int tid = threadIdx.x, r0 = blockIdx.x * 64;

    #pragma unroll
    for (int i = 0; i < 8; ++i) {
        int g = i * 256 + tid;
        int row = g >> 5, c4 = (g & 31) * 4;
        float4 xv = *(const float4*)(x + (r0 + row) * 128 + c4);
        unsigned int byte = (unsigned)(row * 256 + c4 * 2) ^ (unsigned)((row & 7) << 4);
        uint2 pk;
        pk.x = (unsigned)f2b(xv.x) | ((unsigned)f2b(xv.y) << 16);
        pk.y = (unsigned)f2b(xv.z) | ((unsigned)f2b(xv.w) << 16);
        *(uint2*)((char*)xA + byte) = pk;
    }

    int wave = tid >> 6, lane = tid & 63, lrow = lane & 15, lq = lane >> 4;
    f32x4 acc[4][4];
    #pragma unroll
    for (int m = 0; m < 4; ++m)
        #pragma unroll
        for (int n = 0; n < 4; ++n) { f32x4 z = {0.f,0.f,0.f,0.f}; acc[m][n] = z; }

    #pragma unroll
    for (int j = 0; j < 4; ++j) {
        int gr = wave * 256 + j * 64 + lane;
        uint4 w = *(const uint4*)(wsW + 0 * 8192 + gr * 8);
        int n = gr >> 2, q = gr & 3;
        unsigned int byte = (unsigned)(n * 64 + q * 16) ^ (unsigned)((n & 7) << 4);
        *(uint4*)((char*)sW + byte) = w;
    }
    __syncthreads();

    for (int kk = 0; kk < 4; ++kk) {
        int cur = kk & 1;
        uint4 wreg[4];
        if (kk < 3) {
            #pragma unroll
            for (int j = 0; j < 4; ++j) {
                int gr = wave * 256 + j * 64 + lane;
                wreg[j] = *(const uint4*)(wsW + (kk + 1) * 8192 + gr * 8);
            }
        }
        short8 a[4];
        int k = kk * 32 + lq * 8;
        #pragma unroll
        for (int m = 0; m < 4; ++m) {
            unsigned int byte = (unsigned)((m * 16 + lrow) * 256 + k * 2) ^ (unsigned)((lrow & 7) << 4);
            a[m] = *(const short8*)((const char*)xA + byte);
        }
        short8 bfrag[4];
        #pragma unroll
        for (int n = 0; n < 4; ++n) {
            int nr = wave * 64 + n * 16 + lrow;
            unsigned int byte = (unsigned)(nr * 64 + lq * 16) ^ (unsigned)((nr & 7) << 4);
            bfrag[n] = *(const short8*)((const char*)sW + (cur * 16384 + byte));
        }
        #pragma unroll
        for (int m = 0; m < 4; ++m)
            #pragma unroll
            for (int n = 0; n < 4; ++n)
                acc[m][n] = __builtin_amdgcn_mfma_f32_16x16x32_bf16(a[m], bfrag[n], acc[m][n], 0, 0, 0);
        if (kk < 3) {
            int nxt = cur ^ 1;
            #pragma unroll
            for (int j = 0; j < 4; ++j) {
                int gr = wave * 256 + j * 64 + lane;
                int n = gr >> 2, q = gr & 3;
                unsigned int byte = (unsigned)(n * 64 + q * 16) ^ (unsigned)((n & 7) << 4);
                *(uint4*)((char*)sW + (nxt * 16384 + byte)) = wreg[j];
            }
        }
        __syncthreads();
    }

    #pragma unroll
    for (int m = 0; m < 4; ++m)
        #pragma unroll
        for (int n = 0; n < 4; ++n)
            #pragma unroll
            for (int r = 0; r < 4; ++r) {
                int row = m * 16 + lq * 4 + r;
                int col = wave * 64 + n * 16 + lrow;
                float v = acc[m][n][r] + bfv[col];
                basex[(r0 + row) * 256 + col] = f2b(v);
            }
}

__global__ __launch_bounds__(256, 2) void k_step(int t,
                                                 unsigned short* __restrict__ h_ws,
                                                 const float* __restrict__ alpha_in,
                                                 float* __restrict__ alpha_out,
                                                 const unsigned short* __restrict__ basex,
                                                 unsigned short* __restrict__ hu,
                                                 const unsigned short* __restrict__ wsW,
                                                 const float* __restrict__ rs,
                                                 float* __restrict__ norms,
                                                 const float* __restrict__ beta0,
                                                 const int* __restrict__ idxl,
                                                 const int* __restrict__ idxr,
                                                 const float* __restrict__ A_param,
                                                 const float* __restrict__ tau_param) {
    __shared__ unsigned short sA[64 * 256];
    __shared__ unsigned short sW[2 * 8192];
    const int tid = threadIdx.x;
    const int r0 = blockIdx.x * 64;

    StepCtl ctl = step_ctl(norms, t);
    if (!ctl.run && !ctl.upd) return;

    if (ctl.upd) {
        #pragma unroll
        for (int i = 0; i < 8; ++i) {
            int g = i * 256 + tid;
            int row = g >> 5;
            int c8 = (g & 31) * 8;
            int off = (r0 + row) * 256 + c8;
            uint4 hv = *(const uint4*)(h_ws + off);
            uint4 uv = *(const uint4*)(hu + off);
            float hf[8], uf[8], nf[8];
            unpack8(hv, hf); unpack8(uv, uf);
            #pragma unroll
            for (int j = 0; j < 8; ++j) nf[j] = hf[j] + ctl.factor * uf[j];
            *(uint4*)(h_ws + off) = pack8(nf);
        }
    }
    if (!ctl.run) return;
    __syncthreads();

    for (int i = 0; i < 16; ++i) {
        int g = i * 256 + tid;
        int row = g >> 6;
        int c4 = (g & 63) * 4;
        int roff = (r0 + row) * 256;
        float4 av  = *(const float4*)(alpha_in + roff + c4);
        float4 b0v = *(const float4*)(beta0 + roff + c4);
        float4 rv  = *(const float4*)(rs + c4);
        float rsa[4] = {rv.x, rv.y, rv.z, rv.w};
        float aa[4]  = {av.x, av.y, av.z, av.w};
        float bb[4]  = {b0v.x, b0v.y, b0v.z, b0v.w};
        float an[4], sy[4];
        #pragma unroll
        for (int j = 0; j < 4; ++j) {
            int c = c4 + j;
            float hl = b2f(h_ws[roff + idxl[c]]);
            float hr = b2f(h_ws[roff + idxr[c]]);
            float a_new = rsa[j] * aa[j] + hl * hr;
            float p = 1.0f, ss = 0.0f;
            for (int u = 0; u <= t; ++u) { ss += p; p *= rsa[j]; }
            float b_new = p * bb[j] + ss;
            sy[j] = a_new / (sqrtf(b_new) + 1e-6f);
            an[j] = a_new;
        }
        *(float4*)(alpha_out + roff + c4) = make_float4(an[0], an[1], an[2], an[3]);
        unsigned int byte = (unsigned)(row * 512 + c4 * 2) ^ (unsigned)((row & 7) << 4);
        uint2 pk;
        pk.x = (unsigned)f2b(sy[0]) | ((unsigned)f2b(sy[1]) << 16);
        pk.y = (unsigned)f2b(sy[2]) | ((unsigned)f2b(sy[3]) << 16);
        *(uint2*)((char*)sA + byte) = pk;
    }

    const unsigned short* wsrc = wsW + 4 * 8192;
    const int wave = tid >> 6, lane = tid & 63, lrow = lane & 15, lq = lane >> 4;
    f32x4 acc[4][4];
    #pragma unroll
    for (int m = 0; m < 4; ++m)
        #pragma unroll
        for (int n = 0; n < 4; ++n) { f32x4 z = {0.f,0.f,0.f,0.f}; acc[m][n] = z; }

    #pragma unroll
    for (int j = 0; j < 4; ++j) {
        int gr = wave * 256 + j * 64 + lane;
        uint4 w = *(const uint4*)(wsrc + gr * 8);
        int n = gr >> 2, q = gr & 3;
        unsigned int byte = (unsigned)(n * 64 + q * 16) ^ (unsigned)((n & 7) << 4);
        *(uint4*)((char*)sW + byte) = w;
    }
    __syncthreads();

    for (int kk = 0; kk < 16; ++kk) {
        int cur = kk & 1;
        uint4 wreg[4];
        if (kk < 15) {
            #pragma unroll
            for (int j = 0; j < 4; ++j) {
                int gr = wave * 256 + j * 64 + lane;
                wreg[j] = *(const uint4*)(wsrc + (kk + 1) * 8192 + gr * 8);
            }
        }
        short8 a[4];
        if (kk < 8) {
            int k = kk * 32 + lq * 8;
            #pragma unroll
            for (int m = 0; m < 4; ++m) {
                int grow = r0 + m * 16 + lrow;
                a[m] = *(const short8*)(h_ws + grow * 256 + k);
            }
        } else {
            int k = (kk - 8) * 32 + lq * 8;
            #pragma unroll
            for (int m = 0; m < 4; ++m) {
                unsigned int byte = (unsigned)((m * 16 + lrow) * 512 + k * 2) ^ (unsigned)((lrow & 7) << 4);
                a[m] = *(const short8*)((const char*)sA + byte);
            }
        }
        short8 bfrag[4];
        #pragma unroll
        for (int n = 0; n < 4; ++n) {
            int nr = wave * 64 + n * 16 + lrow;
            unsigned int byte = (unsigned)(nr * 64 + lq * 16) ^ (unsigned)((nr & 7) << 4);
            bfrag[n] = *(const short8*)((const char*)sW + (cur * 16384 + byte));
        }
        #pragma unroll
        for (int m = 0; m < 4; ++m)
            #pragma unroll
            for (int n = 0; n < 4; ++n)
                acc[m][n] = __builtin_amdgcn_mfma_f32_16x16x32_bf16(a[m], bfrag[n], acc[m][n], 0, 0, 0);
        if (kk < 15) {
            int nxt = cur ^ 1;
            #pragma unroll
            for (int j = 0; j < 4; ++j) {
                int gr = wave * 256 + j * 64 + lane;
                int n = gr >> 2, q = gr & 3;
                unsigned int byte = (unsigned)(n * 64 + q * 16) ^ (unsigned)((n & 7) << 4);
                *(uint4*)((char*)sW + (nxt * 16384 + byte)) = wreg[j];
            }
        }
        __syncthreads();
    }

    float tauv = tau_param[0];
    float inv_tau = 1.0f / log1pf(expf(tauv));
    float tsum = 0.0f;
    #pragma unroll
    for (int m = 0; m < 4; ++m)
        #pragma unroll
        for (int n = 0; n < 4; ++n)
            #pragma unroll
            for (int r = 0; r < 4; ++r) {
                int row = m * 16 + lq * 4 + r;
                int col = wave * 64 + n * 16 + lrow;
                int off = (r0 + row) * 256 + col;
                float arg = acc[m][n][r] + b2f(basex[off]);
                float s = __sinf(arg);
                float f = s * s;
                float hv = b2f(h_ws[off]);
                float dh = -hv * (inv_tau + f) + A_param[col] * f;
                float huv = 0.1f * dh;
                hu[off] = f2b(huv);
                tsum += fabsf(huv);
            }
    #pragma unroll
    for (int d = 32; d >= 1; d >>= 1) tsum += __shfl_down(tsum, d);
    __syncthreads();
    float* red = (float*)sA;
    if (lane == 0) red[wave] = tsum;
    __syncthreads();
    if (tid == 0) atomicAdd(&norms[t], red[0] + red[1] + red[2] + red[3]);
}

__global__ __launch_bounds__(256) void k_final(const unsigned short* __restrict__ h_ws,
                                               const unsigned short* __restrict__ hu,
                                               const float* __restrict__ alpha_ws,
                                               const float* __restrict__ beta0,
                                               const float* __restrict__ rs,
                                               const float* __restrict__ norms,
                                               float* __restrict__ out) {
    bool done = false, exec5 = false;
    int last = 0;
    float f5 = 2.0f;
    for (int s = 0; s < 6; ++s) {
        if (!done) {
            last = s;
            float nm = norms[s] * (1.0f / 8388608.0f);
            bool brk = (s >= 3) && (nm < 0.01f);
            if (s == 5) { exec5 = true; f5 = brk ? 1.0f : 2.0f; }
            done = done || brk;
        }
    }
    int n_exec = last + 1;

    int tid = threadIdx.x;
    int idx4 = (blockIdx.x * 256 + tid) * 4;

    uint2 hv = *(const uint2*)(h_ws + idx4);
    uint2 uv = *(const uint2*)(hu + idx4);
    float hf[4] = {b2f(hv.x), b2f(hv.x >> 16), b2f(hv.y), b2f(hv.y >> 16)};
    float uf[4] = {b2f(uv.x), b2f(uv.x >> 16), b2f(uv.y), b2f(uv.y >> 16)};
    float4 ho;
    ho.x = exec5 ? (hf[0] + f5 * uf[0]) : hf[0];
    ho.y = exec5 ? (hf[1] + f5 * uf[1]) : hf[1];
    ho.z = exec5 ? (hf[2] + f5 * uf[2]) : hf[2];
    ho.w = exec5 ? (hf[3] + f5 * uf[3]) : hf[3];
    *(float4*)(out + idx4) = ho;

    float4 av = *(const float4*)(alpha_ws + idx4);
    *(float4*)(out + 8388608 + idx4) = av;

    int c0 = idx4 & 255;
    float4 b0v = *(const float4*)(beta0 + idx4);
    float4 rv  = *(const float4*)(rs + c0);
    float bb[4] = {b0v.x, b0v.y, b0v.z, b0v.w};
    float rr[4] = {rv.x, rv.y, rv.z, rv.w};
    float4 bo;
    float* bop = (float*)&bo;
    #pragma unroll
    for (int j = 0; j < 4; ++j) {
        float p = 1.0f, ss = 0.0f;
        for (int u = 0; u < n_exec; ++u) { ss += p; p *= rr[j]; }
        bop[j] = p * bb[j] + ss;
    }
    *(float4*)(out + 16777216 + idx4) = bo;

    if (blockIdx.x == 0 && tid == 0) out[25165824] = (float)last;
}

// ---------------------------------------------------------------------------
extern "C" void kernel_launch(void* const* d_in, const int* in_sizes, int n_in,
                              void* d_out, int out_size, void* d_ws, size_t ws_size,
                              hipStream_t stream) {
    const float* x      = (const float*)d_in[0];
    const float* h0     = (const float*)d_in[1];
    const float* alpha0 = (const float*)d_in[2];
    const float* beta0  = (const float*)d_in[3];
    const float* Wf     = (const float*)d_in[4];
    const float* bfv    = (const float*)d_in[5];
    const float* tau    = (const float*)d_in[6];
    const float* rparam = (const float*)d_in[7];
    const float* Aparam = (const float*)d_in[8];
    const float* Wm     = (const float*)d_in[9];
    const int* idxl     = (const int*)d_in[10];
    const int* idxr     = (const int*)d_in[11];

    char* ws = (char*)d_ws;
    float* out = (float*)d_out;

    // ---- primary path: persistent cooperative kernel
    {
        unsigned short* wsWp  = (unsigned short*)(ws);        // 320KB
        float*          normp = (float*)(ws + 327680);        // 32B
        uint4*          bxg   = (uint4*)(ws + 393216);        // 16.78MB
        void* args[] = {
            (void*)&x, (void*)&h0, (void*)&alpha0, (void*)&beta0,
            (void*)&Wf, (void*)&bfv, (void*)&tau, (void*)&rparam,
            (void*)&Aparam, (void*)&Wm, (void*)&idxl, (void*)&idxr,
            (void*)&wsWp, (void*)&normp, (void*)&bxg, (void*)&out
        };
        hipError_t err = hipLaunchCooperativeKernel((const void*)k_persist,
                                                    dim3(512), dim3(256),
                                                    args, 0, stream);
        if (err == hipSuccess) return;
    }

    // ---- fallback path: round-2 proven multi-kernel sequence
    unsigned short* h_ws  = (unsigned short*)(ws + 0);
    float*          alpha = (float*)(ws + 16777216);
    unsigned short* basex = (unsigned short*)(ws + 50331648);
    unsigned short* hu    = (unsigned short*)(ws + 67108864);
    unsigned short* wsW   = (unsigned short*)(ws + 83886080);
    float*          rs    = (float*)(ws + 84213760);
    float*          norms = (float*)(ws + 84214784);

    k_init<<<8273, 256, 0, stream>>>(h0, Wf, Wm, rparam, h_ws, wsW, rs, norms);
    k_basex<<<512, 256, 0, stream>>>(x, bfv, wsW, basex);
    for (int t = 0; t < 6; ++t) {
        const float* a_in = (t == 0) ? alpha0 : alpha;
        k_step<<<512, 256, 0, stream>>>(t, h_ws, a_in, alpha, basex, hu, wsW, rs, norms,
                                        beta0, idxl, idxr, Aparam, tau);
    }
    k_final<<<8192, 256, 0, stream>>>(h_ws, hu, alpha, beta0, rs, norms, out);
}

// Round 5
// 319.870 us; speedup vs baseline: 2.2793x; 2.2793x over previous
//
#include <hip/hip_runtime.h>
#include <hip/hip_bf16.h>
#include <math.h>

// Problem constants
#define NB 32768   // batch
#define NH 256     // hidden = nsync
#define NI 128     // input
// out layout (f32): h[8388608] | alpha[8388608] | beta[8388608] | last[1]
// alpha is written in-place by k_step directly into out's alpha region.

typedef __attribute__((ext_vector_type(8))) short short8;  // 8 x bf16 mfma frag
typedef __attribute__((ext_vector_type(4))) float f32x4;   // mfma accum

__device__ __forceinline__ float b2f(unsigned int u) {
    union { float f; unsigned int i; } v; v.i = (u & 0xffffu) << 16; return v.f;
}
__device__ __forceinline__ unsigned short f2b(float f) {
    union { float f; unsigned int i; } v; v.f = f;
    unsigned int x = v.i;
    return (unsigned short)((x + 0x7fffu + ((x >> 16) & 1u)) >> 16);
}
__device__ __forceinline__ void unpack8(uint4 v, float* o) {
    o[0]=b2f(v.x); o[1]=b2f(v.x>>16);
    o[2]=b2f(v.y); o[3]=b2f(v.y>>16);
    o[4]=b2f(v.z); o[5]=b2f(v.z>>16);
    o[6]=b2f(v.w); o[7]=b2f(v.w>>16);
}
__device__ __forceinline__ uint4 pack8(const float* f) {
    uint4 r;
    r.x = (unsigned)f2b(f[0]) | ((unsigned)f2b(f[1])<<16);
    r.y = (unsigned)f2b(f[2]) | ((unsigned)f2b(f[3])<<16);
    r.z = (unsigned)f2b(f[4]) | ((unsigned)f2b(f[5])<<16);
    r.w = (unsigned)f2b(f[6]) | ((unsigned)f2b(f[7])<<16);
    return r;
}

// scalar per-step control from norm accumulators (proven round 2)
struct StepCtl { bool run; bool upd; float factor; };
__device__ __forceinline__ StepCtl step_ctl(const float* norms, int t) {
    bool done = false, done_prev = false, brk_prev = false;
    for (int s = 0; s < t; ++s) {
        bool brk = false;
        if (!done) {
            float nm = norms[s] * (1.0f / 8388608.0f);
            brk = (s >= 3) && (nm < 0.01f);
        }
        if (s == t - 1) { done_prev = done; brk_prev = brk; }
        done = done || brk;
    }
    StepCtl c;
    c.upd = (t > 0) && !done_prev;
    c.factor = brk_prev ? 1.0f : 2.0f;
    c.run = !done;
    return c;
}

// ---------------------------------------------------------------------------
// k_init: h0->bf16, beta0->bf16, W->bf16 fragment-major slices, rs, norms=0.
// W layout: slice s (K-chunk of 32), addr = s*8192 + (q*256 + n)*8 shorts,
//           holding W[n][s*32+q*8 .. +8)  (q = k-subgroup = lane>>4 at read).
// blocks: 0..4095 h | 4096..8191 beta0 | 8192..8271 W | 8272 rs+norms
// ---------------------------------------------------------------------------
__global__ __launch_bounds__(256) void k_init(const float* __restrict__ h0,
                                              const float* __restrict__ beta0,
                                              const float* __restrict__ Wf,
                                              const float* __restrict__ Wm,
                                              const float* __restrict__ r_param,
                                              unsigned short* __restrict__ h_ws,
                                              unsigned short* __restrict__ b0b,
                                              unsigned short* __restrict__ wsW,
                                              float* __restrict__ rs,
                                              float* __restrict__ norms) {
    int b = blockIdx.x, tid = threadIdx.x;
    if (b < 4096) {
        int idx = b * 2048 + tid * 8;
        float4 v0 = *(const float4*)(h0 + idx), v1 = *(const float4*)(h0 + idx + 4);
        float vf[8] = {v0.x, v0.y, v0.z, v0.w, v1.x, v1.y, v1.z, v1.w};
        *(uint4*)(h_ws + idx) = pack8(vf);
    } else if (b < 8192) {
        int idx = (b - 4096) * 2048 + tid * 8;
        float4 v0 = *(const float4*)(beta0 + idx), v1 = *(const float4*)(beta0 + idx + 4);
        float vf[8] = {v0.x, v0.y, v0.z, v0.w, v1.x, v1.y, v1.z, v1.w};
        *(uint4*)(b0b + idx) = pack8(vf);
    } else if (b < 8272) {
        int gt = (b - 8192) * 256 + tid;       // 0..20479
        int s = gt >> 10, rem = gt & 1023;
        int n = rem >> 2, q = rem & 3;
        float vals[8];
        #pragma unroll
        for (int j = 0; j < 8; ++j) {
            int kg = s * 32 + q * 8 + j;       // global K index 0..639
            vals[j] = (kg < 384) ? Wf[n * 384 + kg] : Wm[n * 256 + (kg - 384)];
        }
        *(uint4*)(wsW + s * 8192 + (q * 256 + n) * 8) = pack8(vals);
    } else {
        rs[tid] = 1.0f / (1.0f + expf(-r_param[tid]));
        if (tid < 8) norms[tid] = 0.0f;
    }
}

// ---------------------------------------------------------------------------
// k_basex: base_x = x @ Wfx^T + bf  (bf16 out). BM=32, 1024 blocks, 4 waves.
// ---------------------------------------------------------------------------
__global__ __launch_bounds__(256, 4) void k_basex(const float* __restrict__ x,
                                                  const float* __restrict__ bfv,
                                                  const unsigned short* __restrict__ wsW,
                                                  unsigned short* __restrict__ basex) {
    __shared__ unsigned short sX[32 * 128];    // 8KB, swizzled (row stride 256B)
    const int tid = threadIdx.x, r0 = blockIdx.x * 32;
    const int prow = tid >> 3;
    const unsigned pswz = (unsigned)((prow & 7) << 4);

    // stage x -> bf16 LDS
    #pragma unroll
    for (int k = 0; k < 4; ++k) {
        int c = (tid & 7) * 4 + k * 32;
        float4 v = *(const float4*)(x + (r0 + prow) * 128 + c);
        uint2 pk;
        pk.x = (unsigned)f2b(v.x) | ((unsigned)f2b(v.y) << 16);
        pk.y = (unsigned)f2b(v.z) | ((unsigned)f2b(v.w) << 16);
        *(uint2*)((char*)sX + (((unsigned)(prow * 256 + c * 2)) ^ pswz)) = pk;
    }
    __syncthreads();

    const int wave = tid >> 6, lane = tid & 63, lrow = lane & 15, lq = lane >> 4;
    const unsigned aswz = (unsigned)((lrow & 7) << 4);
    const int fragoff = (lq * 256 + wave * 64 + lrow) * 8;

    f32x4 acc[2][4];
    #pragma unroll
    for (int m = 0; m < 2; ++m)
        #pragma unroll
        for (int n = 0; n < 4; ++n) { f32x4 z = {0.f,0.f,0.f,0.f}; acc[m][n] = z; }

    #pragma unroll
    for (int kk = 0; kk < 4; ++kk) {
        short8 bfr[4];
        #pragma unroll
        for (int n = 0; n < 4; ++n)
            bfr[n] = *(const short8*)(wsW + kk * 8192 + fragoff + n * 128);
        short8 a[2];
        int kb = (kk * 32 + lq * 8) * 2;
        #pragma unroll
        for (int m = 0; m < 2; ++m)
            a[m] = *(const short8*)((const char*)sX +
                    (((unsigned)((m * 16 + lrow) * 256 + kb)) ^ aswz));
        #pragma unroll
        for (int m = 0; m < 2; ++m)
            #pragma unroll
            for (int n = 0; n < 4; ++n)
                acc[m][n] = __builtin_amdgcn_mfma_f32_16x16x32_bf16(a[m], bfr[n], acc[m][n], 0, 0, 0);
    }

    #pragma unroll
    for (int n = 0; n < 4; ++n) {
        int col = wave * 64 + n * 16 + lrow;
        float bias = bfv[col];
        #pragma unroll
        for (int m = 0; m < 2; ++m)
            #pragma unroll
            for (int r = 0; r < 4; ++r) {
                int row = m * 16 + lq * 4 + r;      // C/D: col=lane&15, row=(lane>>4)*4+reg
                basex[(r0 + row) * 256 + col] = f2b(acc[m][n][r] + bias);
            }
    }
}

// ---------------------------------------------------------------------------
// k_step: one recurrent step. BM=32, 1024 blocks x 256 thr, 4 blocks/CU.
// ---------------------------------------------------------------------------
__global__ __launch_bounds__(256, 4) void k_step(int t,
        unsigned short* __restrict__ h_ws, unsigned short* __restrict__ hu,
        const unsigned short* __restrict__ basex, const unsigned short* __restrict__ b0b,
        const unsigned short* __restrict__ wsW, const float* __restrict__ rs,
        float* __restrict__ norms,
        const float* __restrict__ alpha0, float* __restrict__ alpha_io,
        const int* __restrict__ idxl, const int* __restrict__ idxr,
        const float* __restrict__ Aparam, const float* __restrict__ tau) {
    __shared__ unsigned short sH[32 * 256];   // 16KB h tile (swizzled)
    __shared__ unsigned short sA[32 * 256];   // 16KB sync tile (swizzled)
    __shared__ int   pIdx[256];
    __shared__ float rsL[256], btP[256], btS[256];
    __shared__ float red[4];

    const int tid = threadIdx.x;
    const int r0 = blockIdx.x * 32;

    StepCtl ctl = step_ctl(norms, t);
    if (!ctl.run && !ctl.upd) return;

    {   // per-col tables (barrier below covers visibility)
        float rr = rs[tid];
        rsL[tid]  = rr;
        pIdx[tid] = (idxl[tid] & 0xffff) | (idxr[tid] << 16);
        float p = 1.0f, ssum = 0.0f;
        for (int u = 0; u <= t; ++u) { ssum += p; p *= rr; }
        btP[tid] = p; btS[tid] = ssum;        // beta_{t+1} = p*beta0 + ssum
    }

    const int prow = tid >> 3;
    const unsigned pswz = (unsigned)((prow & 7) << 4);

    // ---- phase A: apply previous step's h update; stage h -> sH
    #pragma unroll
    for (int k = 0; k < 4; ++k) {
        int c = (tid & 7) * 8 + k * 64;
        int off = (r0 + prow) * 256 + c;
        uint4 hv = *(const uint4*)(h_ws + off);
        if (ctl.upd) {
            uint4 uv = *(const uint4*)(hu + off);
            float hf[8], uf[8], nf[8];
            unpack8(hv, hf); unpack8(uv, uf);
            #pragma unroll
            for (int j = 0; j < 8; ++j) nf[j] = hf[j] + ctl.factor * uf[j];
            hv = pack8(nf);
            *(uint4*)(h_ws + off) = hv;
        }
        *(uint4*)((char*)sH + (((unsigned)(prow * 512 + c * 2)) ^ pswz)) = hv;
    }
    if (!ctl.run) return;   // block-uniform
    __syncthreads();

    // ---- phase B: alpha recurrence + sync -> sA; alpha written in place (out)
    #pragma unroll
    for (int k = 0; k < 8; ++k) {
        int c = (tid & 7) * 4 + k * 32;
        int off = (r0 + prow) * 256 + c;
        float4 av = (t == 0) ? *(const float4*)(alpha0 + off)
                             : *(const float4*)(alpha_io + off);
        uint2 b0v = *(const uint2*)(b0b + off);
        float bb[4] = {b2f(b0v.x), b2f(b0v.x >> 16), b2f(b0v.y), b2f(b0v.y >> 16)};
        float aa[4] = {av.x, av.y, av.z, av.w};
        float sy[4];
        #pragma unroll
        for (int j = 0; j < 4; ++j) {
            int cj = c + j;
            int pr = pIdx[cj];
            float hl = b2f(*(const unsigned short*)((const char*)sH +
                       (((unsigned)(prow * 512 + (pr & 0xffff) * 2)) ^ pswz)));
            float hr = b2f(*(const unsigned short*)((const char*)sH +
                       (((unsigned)(prow * 512 + (pr >> 16) * 2)) ^ pswz)));
            float a_new = rsL[cj] * aa[j] + hl * hr;
            aa[j] = a_new;
            float bt = btP[cj] * bb[j] + btS[cj];
            sy[j] = a_new / (sqrtf(bt) + 1e-6f);
        }
        *(float4*)(alpha_io + off) = make_float4(aa[0], aa[1], aa[2], aa[3]);
        uint2 pk;
        pk.x = (unsigned)f2b(sy[0]) | ((unsigned)f2b(sy[1]) << 16);
        pk.y = (unsigned)f2b(sy[2]) | ((unsigned)f2b(sy[3]) << 16);
        *(uint2*)((char*)sA + (((unsigned)(prow * 512 + c * 2)) ^ pswz)) = pk;
    }
    __syncthreads();

    // ---- GEMM: [h | sync] (32x512) @ [Wfh|Wm]^T -> 32x256
    const int wave = tid >> 6, lane = tid & 63, lrow = lane & 15, lq = lane >> 4;
    const unsigned aswz = (unsigned)((lrow & 7) << 4);
    const int fragoff = (lq * 256 + wave * 64 + lrow) * 8;
    const unsigned short* wstep = wsW + 4 * 8192;   // slices 4..19

    f32x4 acc[2][4];
    #pragma unroll
    for (int m = 0; m < 2; ++m)
        #pragma unroll
        for (int n = 0; n < 4; ++n) { f32x4 z = {0.f,0.f,0.f,0.f}; acc[m][n] = z; }

    #pragma unroll 1
    for (int kk = 0; kk < 16; ++kk) {
        short8 bfr[4];
        #pragma unroll
        for (int n = 0; n < 4; ++n)
            bfr[n] = *(const short8*)(wstep + kk * 8192 + fragoff + n * 128);
        const char* src = (kk < 8) ? (const char*)sH : (const char*)sA;
        int kb = ((kk & 7) * 32 + lq * 8) * 2;
        short8 a[2];
        #pragma unroll
        for (int m = 0; m < 2; ++m)
            a[m] = *(const short8*)(src + (((unsigned)((m * 16 + lrow) * 512 + kb)) ^ aswz));
        #pragma unroll
        for (int m = 0; m < 2; ++m)
            #pragma unroll
            for (int n = 0; n < 4; ++n)
                acc[m][n] = __builtin_amdgcn_mfma_f32_16x16x32_bf16(a[m], bfr[n], acc[m][n], 0, 0, 0);
    }

    // ---- epilogue: f=sin(base+drive)^2, hu (global), norm partial
    const float inv_tau = 1.0f / log1pf(expf(tau[0]));
    float Areg[4];
    #pragma unroll
    for (int n = 0; n < 4; ++n) Areg[n] = Aparam[wave * 64 + n * 16 + lrow];
    float tsum = 0.0f;
    #pragma unroll
    for (int m = 0; m < 2; ++m)
        #pragma unroll
        for (int n = 0; n < 4; ++n) {
            int col = wave * 64 + n * 16 + lrow;
            #pragma unroll
            for (int r = 0; r < 4; ++r) {
                int row = m * 16 + lq * 4 + r;
                int off = (r0 + row) * 256 + col;
                float arg = acc[m][n][r] + b2f(basex[off]);
                float s = __sinf(arg);
                float fv = s * s;
                float hv = b2f(*(const unsigned short*)((const char*)sH +
                           (((unsigned)(row * 512 + col * 2)) ^ ((unsigned)((row & 7) << 4)))));
                float dh = -hv * (inv_tau + fv) + Areg[n] * fv;
                float huv = 0.1f * dh;
                hu[off] = f2b(huv);
                tsum += fabsf(huv);
            }
        }
    #pragma unroll
    for (int d = 32; d >= 1; d >>= 1) tsum += __shfl_down(tsum, d);
    if (lane == 0) red[wave] = tsum;
    __syncthreads();
    if (tid == 0) atomicAdd(&norms[t], red[0] + red[1] + red[2] + red[3]);
}

// ---------------------------------------------------------------------------
// k_final: last h update + h,beta,last outputs (alpha already in out).
// ---------------------------------------------------------------------------
__global__ __launch_bounds__(256) void k_final(const unsigned short* __restrict__ h_ws,
                                               const unsigned short* __restrict__ hu,
                                               const unsigned short* __restrict__ b0b,
                                               const float* __restrict__ rs,
                                               const float* __restrict__ norms,
                                               float* __restrict__ out) {
    bool done = false, exec5 = false;
    int last = 0;
    float f5 = 2.0f;
    for (int s = 0; s < 6; ++s) {
        if (!done) {
            last = s;
            float nm = norms[s] * (1.0f / 8388608.0f);
            bool brk = (s >= 3) && (nm < 0.01f);
            if (s == 5) { exec5 = true; f5 = brk ? 1.0f : 2.0f; }
            done = done || brk;
        }
    }
    int n_exec = last + 1;

    int base = (blockIdx.x * 256 + threadIdx.x) * 16;
    #pragma unroll
    for (int c8 = 0; c8 < 2; ++c8) {
        int off = base + c8 * 8;
        uint4 hv = *(const uint4*)(h_ws + off);
        float hf[8];
        unpack8(hv, hf);
        if (exec5) {
            uint4 uv = *(const uint4*)(hu + off);
            float uf[8];
            unpack8(uv, uf);
            #pragma unroll
            for (int j = 0; j < 8; ++j) hf[j] += f5 * uf[j];
        }
        *(float4*)(out + off)     = make_float4(hf[0], hf[1], hf[2], hf[3]);
        *(float4*)(out + off + 4) = make_float4(hf[4], hf[5], hf[6], hf[7]);

        uint4 bv = *(const uint4*)(b0b + off);
        float bb[8];
        unpack8(bv, bb);
        int c0 = off & 255;
        float bo[8];
        #pragma unroll
        for (int j = 0; j < 8; ++j) {
            float rr = rs[c0 + j];
            float p = 1.0f, ss = 0.0f;
            for (int u = 0; u < n_exec; ++u) { ss += p; p *= rr; }
            bo[j] = p * bb[j] + ss;
        }
        *(float4*)(out + 16777216 + off)     = make_float4(bo[0], bo[1], bo[2], bo[3]);
        *(float4*)(out + 16777216 + off + 4) = make_float4(bo[4], bo[5], bo[6], bo[7]);
    }
    if (blockIdx.x == 0 && threadIdx.x == 0) out[25165824] = (float)last;
}

// ---------------------------------------------------------------------------
extern "C" void kernel_launch(void* const* d_in, const int* in_sizes, int n_in,
                              void* d_out, int out_size, void* d_ws, size_t ws_size,
                              hipStream_t stream) {
    const float* x      = (const float*)d_in[0];
    const float* h0     = (const float*)d_in[1];
    const float* alpha0 = (const float*)d_in[2];
    const float* beta0  = (const float*)d_in[3];
    const float* Wf     = (const float*)d_in[4];
    const float* bfv    = (const float*)d_in[5];
    const float* tau    = (const float*)d_in[6];
    const float* rparam = (const float*)d_in[7];
    const float* Aparam = (const float*)d_in[8];
    const float* Wm     = (const float*)d_in[9];
    const int* idxl     = (const int*)d_in[10];
    const int* idxr     = (const int*)d_in[11];

    char* ws = (char*)d_ws;
    unsigned short* h_ws  = (unsigned short*)(ws + 0);           // bf16 16.78MB
    unsigned short* hu    = (unsigned short*)(ws + 16777216);    // bf16 16.78MB
    unsigned short* basex = (unsigned short*)(ws + 33554432);    // bf16 16.78MB
    unsigned short* b0b   = (unsigned short*)(ws + 50331648);    // bf16 16.78MB
    unsigned short* wsW   = (unsigned short*)(ws + 67108864);    // bf16 20x8192 = 320KB
    float*          rs    = (float*)(ws + 67436544);             // f32 [256]
    float*          norms = (float*)(ws + 67437568);             // f32 [8]

    float* out = (float*)d_out;
    float* alpha_io = out + 8388608;   // alpha region of output, updated in place

    k_init<<<8273, 256, 0, stream>>>(h0, beta0, Wf, Wm, rparam, h_ws, b0b, wsW, rs, norms);
    k_basex<<<1024, 256, 0, stream>>>(x, bfv, wsW, basex);
    for (int t = 0; t < 6; ++t)
        k_step<<<1024, 256, 0, stream>>>(t, h_ws, hu, basex, b0b, wsW, rs, norms,
                                         alpha0, alpha_io, idxl, idxr, Aparam, tau);
    k_final<<<2048, 256, 0, stream>>>(h_ws, hu, b0b, rs, norms, out);
}